// Round 7
// baseline (102.965 us; speedup 1.0000x reference)
//
#include <hip/hip_runtime.h>
#include <math.h>

#define BATCH 16384
#define NS 4
#define NBLK (BATCH/NS)  // 4096

// ---- ws float offsets ----
#define RT    0        // [192][20] {TQ4,BQ4,We4,be4,Wo4} (TQ/BQ pre-scaled 0.5)
#define A12   3840     // [96][32][2] {A1,A2}
#define TD1   9984     // [96][32]
#define TKT   13056    // [96][8]
#define TVT   13824    // [96][8]
#define A0T   14592    // [32]
#define CD1   14624    // [32]
#define SBK   14656    // [8]
#define SBV   14664    // [8]
#define WD2T  14672    // [16][32]

// ---- LDS layout (floats), module arrays skewed +4/module for banks ----
#define XO(m,f)   ((m)*164 + (f)*4)          // region A: x   [0, 980)
#define H2O(m,k)  ((m)*132 + (k)*4)          // region A: h2  [0, 788)
#define H1O(m,k)  (980 + (m)*260 + (k)*4)    // h1  [980, 2536)
#define FO(t)     (980 + (t)*4)              // flat  [980,1364)
#define F2O(t)    (1364 + (t)*4)             // flat2 [1364,1748)
#define PO(e,c)   (1748 + ((e)*2+(c))*4)     // partials [1748,2388)
#define SO(e)     (2388 + (e)*4)             // stats [2388,2708)
#define RO        2708                        // red [2708,2724)
#define SSZ       2724

__device__ __forceinline__ float4 f4_fma(float4 a, float s, float4 c) {
    return make_float4(fmaf(a.x,s,c.x), fmaf(a.y,s,c.y), fmaf(a.z,s,c.z), fmaf(a.w,s,c.w));
}
__device__ __forceinline__ float4 f4_relu(float4 a) {
    return make_float4(fmaxf(a.x,0.f),fmaxf(a.y,0.f),fmaxf(a.z,0.f),fmaxf(a.w,0.f));
}
__device__ __forceinline__ float4 f4_adds(float4 a, float s) {
    return make_float4(a.x+s, a.y+s, a.z+s, a.w+s);
}

// ---------------- table kernel ----------------
__global__ __launch_bounds__(256) void table_kernel(
    const float* __restrict__ We, const float* __restrict__ be,
    const float* __restrict__ Wq, const float* __restrict__ Wk,
    const float* __restrict__ Wv, const float* __restrict__ Wd1,
    const float* __restrict__ bd1, const float* __restrict__ Wo,
    const float* __restrict__ Wd2,
    float* __restrict__ ws)
{
    int t = blockIdx.x * 256 + threadIdx.x;
    if (t < 3840) {                       // ROWTAB
        int r = t / 20, c = t % 20;
        int h = r / 96, q = r % 96;
        float v;
        if (c < 4) {
            float a = 0.f;
            #pragma unroll
            for (int i = 0; i < 8; ++i) a += We[q*8+i] * Wq[i*8 + h*4 + c];
            v = 0.5f * a;
        } else if (c < 8) {
            float a = 0.f;
            #pragma unroll
            for (int i = 0; i < 8; ++i) a += be[q*8+i] * Wq[i*8 + h*4 + (c-4)];
            v = 0.5f * a;
        } else if (c < 12) {
            v = We[q*8 + h*4 + (c-8)];
        } else if (c < 16) {
            v = be[q*8 + h*4 + (c-12)];
        } else {
            v = Wo[16 + q*8 + h*4 + (c-16)];
        }
        ws[RT + t] = v;
    } else if (t < 6912) {                // A12 [tok][g][2]
        int l = t - 3840, tok = l >> 5, g = l & 31;
        int h = g >> 4, d = (g >> 2) & 3, e = g & 3;
        float tk = 0.f, bk = 0.f, tv = 0.f, bv = 0.f;
        #pragma unroll
        for (int j = 0; j < 8; ++j) {
            float we = We[tok*8+j], b = be[tok*8+j];
            tk += we * Wk[j*8 + h*4 + d]; bk += b * Wk[j*8 + h*4 + d];
            tv += we * Wv[j*8 + h*4 + e]; bv += b * Wv[j*8 + h*4 + e];
        }
        ws[A12 + l*2]     = tk*bv + bk*tv;
        ws[A12 + l*2 + 1] = tk*tv;
    } else if (t < 9984) {                // TD1 [tok][32]
        int l = t - 6912, tok = l >> 5, g = l & 31;
        float a = 0.f;
        #pragma unroll
        for (int j = 0; j < 8; ++j) a += We[tok*8+j] * Wd1[(tok*8+j)*32 + g];
        ws[TD1 + l] = a;
    } else if (t < 11520) {               // TKT/TVT [tok][8]
        int l = t - 9984;
        int isV = l / 768, rem = l % 768;
        int tok = rem >> 3, d = rem & 7;
        const float* W = isV ? Wv : Wk;
        float a = 0.f;
        #pragma unroll
        for (int j = 0; j < 8; ++j) a += We[tok*8+j] * W[j*8 + d];
        ws[(isV ? TVT : TKT) + rem] = a;
    } else if (t < 11776) {               // A0T
        int l = t - 11520, g = l >> 3, c = l & 7;
        int h = g >> 4, d = (g >> 2) & 3, e = g & 3;
        float acc = 0.f;
        for (int tok = c*12; tok < c*12 + 12; ++tok) {
            float bk = 0.f, bv = 0.f;
            #pragma unroll
            for (int j = 0; j < 8; ++j) {
                float b = be[tok*8+j];
                bk += b * Wk[j*8 + h*4 + d];
                bv += b * Wv[j*8 + h*4 + e];
            }
            acc += bk * bv;
        }
        acc += __shfl_xor(acc,1); acc += __shfl_xor(acc,2); acc += __shfl_xor(acc,4);
        if (c == 0) ws[A0T + g] = acc;
    } else if (t < 12032) {               // CD1
        int l = t - 11776, g = l >> 3, c = l & 7;
        float acc = 0.f;
        for (int i = c*96; i < c*96 + 96; ++i) acc += be[i] * Wd1[i*32 + g];
        acc += __shfl_xor(acc,1); acc += __shfl_xor(acc,2); acc += __shfl_xor(acc,4);
        if (c == 0) ws[CD1 + g] = acc + bd1[g];
    } else if (t < 12288) {               // SBK/SBV
        int l = t - 12032, idx = l >> 4, c = l & 15;
        int isV = idx >> 3, d = idx & 7;
        const float* W = isV ? Wv : Wk;
        float acc = 0.f;
        for (int i = c*48; i < c*48 + 48; ++i) acc += be[i] * W[(i & 7)*8 + d];
        acc += __shfl_xor(acc,1); acc += __shfl_xor(acc,2);
        acc += __shfl_xor(acc,4); acc += __shfl_xor(acc,8);
        if (c == 0) ws[(isV ? SBV : SBK) + d] = acc;
    } else if (t < 12800) {               // WD2T [16][32]
        int l = t - 12288, o = l >> 5, k = l & 31;
        ws[WD2T + l] = Wd2[k*16 + o];
    }
}

// ---------------- main kernel: NS=4, quad-output (no shuffles) ----------------
__global__ __launch_bounds__(256) void autoint_kernel(
    const float* __restrict__ mod_fea,
    const float* __restrict__ W1, const float* __restrict__ b1,
    const float* __restrict__ W2, const float* __restrict__ b2,
    const float* __restrict__ W3, const float* __restrict__ b3,
    const float* __restrict__ bd2,
    const float* __restrict__ Wo, const float* __restrict__ bo,
    const float* __restrict__ ws,
    float* __restrict__ out)
{
    const int tid  = threadIdx.x;
    const int blk  = blockIdx.x;
    const int lane = tid & 63;
    const int wv   = tid >> 6;

    __shared__ __align__(16) float S[SSZ];

    // ---- P0: load 4 rows, transpose to skewed xT ----
    {
        const float* xin = mod_fea + (size_t)blk * 960;
        for (int e = tid; e < 960; e += 256) {
            int s = e / 240, f = e - s*240;
            int m = f / 40, ff = f - m*40;
            S[XO(m,ff) + s] = xin[e];
        }
    }
    __syncthreads();

    // ---- P1: h1, 96 quad-tasks ----
    if (tid < 96) {
        int m = tid >> 4, og = (tid & 15) * 4;
        const float* wp = W1 + m*2560 + og;
        float4 A0 = make_float4(0,0,0,0), A1 = A0, A2 = A0, A3 = A0;
        #pragma unroll 8
        for (int f = 0; f < 40; ++f) {
            float4 xv = *(const float4*)(S + XO(m,f));
            float4 w  = *(const float4*)(wp + f*64);
            A0 = f4_fma(xv, w.x, A0); A1 = f4_fma(xv, w.y, A1);
            A2 = f4_fma(xv, w.z, A2); A3 = f4_fma(xv, w.w, A3);
        }
        float4 bb = *(const float4*)(b1 + m*64 + og);
        *(float4*)(S + H1O(m, og+0)) = f4_relu(f4_adds(A0, bb.x));
        *(float4*)(S + H1O(m, og+1)) = f4_relu(f4_adds(A1, bb.y));
        *(float4*)(S + H1O(m, og+2)) = f4_relu(f4_adds(A2, bb.z));
        *(float4*)(S + H1O(m, og+3)) = f4_relu(f4_adds(A3, bb.w));
    }
    __syncthreads();

    // ---- P2: h2, 48 quad-tasks ----
    if (tid < 48) {
        int m = tid >> 3, og = (tid & 7) * 4;
        const float* wp = W2 + m*2048 + og;
        float4 A0 = make_float4(0,0,0,0), A1 = A0, A2 = A0, A3 = A0;
        #pragma unroll 8
        for (int k = 0; k < 64; ++k) {
            float4 xv = *(const float4*)(S + H1O(m,k));
            float4 w  = *(const float4*)(wp + k*32);
            A0 = f4_fma(xv, w.x, A0); A1 = f4_fma(xv, w.y, A1);
            A2 = f4_fma(xv, w.z, A2); A3 = f4_fma(xv, w.w, A3);
        }
        float4 bb = *(const float4*)(b2 + m*32 + og);
        *(float4*)(S + H2O(m, og+0)) = f4_relu(f4_adds(A0, bb.x));
        *(float4*)(S + H2O(m, og+1)) = f4_relu(f4_adds(A1, bb.y));
        *(float4*)(S + H2O(m, og+2)) = f4_relu(f4_adds(A2, bb.z));
        *(float4*)(S + H2O(m, og+3)) = f4_relu(f4_adds(A3, bb.w));
    }
    __syncthreads();

    // ---- P3: flat + flat^2, 24 quad-tasks ----
    if (tid < 24) {
        int m = tid >> 2, og = (tid & 3) * 4;
        const float* wp = W3 + m*512 + og;
        float4 A0 = make_float4(0,0,0,0), A1 = A0, A2 = A0, A3 = A0;
        #pragma unroll 8
        for (int k = 0; k < 32; ++k) {
            float4 xv = *(const float4*)(S + H2O(m,k));
            float4 w  = *(const float4*)(wp + k*16);
            A0 = f4_fma(xv, w.x, A0); A1 = f4_fma(xv, w.y, A1);
            A2 = f4_fma(xv, w.z, A2); A3 = f4_fma(xv, w.w, A3);
        }
        float4 bb = *(const float4*)(b3 + m*16 + og);
        int t0 = m*16 + og;
        float4 F0 = f4_relu(f4_adds(A0, bb.x));
        float4 F1 = f4_relu(f4_adds(A1, bb.y));
        float4 F2 = f4_relu(f4_adds(A2, bb.z));
        float4 F3 = f4_relu(f4_adds(A3, bb.w));
        *(float4*)(S + FO(t0+0)) = F0;
        *(float4*)(S + FO(t0+1)) = F1;
        *(float4*)(S + FO(t0+2)) = F2;
        *(float4*)(S + FO(t0+3)) = F3;
        *(float4*)(S + F2O(t0+0)) = make_float4(F0.x*F0.x,F0.y*F0.y,F0.z*F0.z,F0.w*F0.w);
        *(float4*)(S + F2O(t0+1)) = make_float4(F1.x*F1.x,F1.y*F1.y,F1.z*F1.z,F1.w*F1.w);
        *(float4*)(S + F2O(t0+2)) = make_float4(F2.x*F2.x,F2.y*F2.y,F2.z*F2.z,F2.w*F2.w);
        *(float4*)(S + F2O(t0+3)) = make_float4(F3.x*F3.x,F3.y*F3.y,F3.z*F3.z,F3.w*F3.w);
    }
    __syncthreads();

    // ---- P4a: partial stats (k-split 2, LDS combine; 40 tasks) ----
    if (tid < 16) {                        // G: 8 quads x 2 chunks
        int gq = tid >> 1, c = tid & 1;
        const float* a12p = ws + A12 + 8*gq;
        float4 A0 = make_float4(0,0,0,0), A1 = A0, A2 = A0, A3 = A0;
        #pragma unroll 4
        for (int i = 0; i < 48; ++i) {
            int tok = c*48 + i;
            float4 f1 = *(const float4*)(S + FO(tok));
            float4 f2 = *(const float4*)(S + F2O(tok));
            float4 lo = *(const float4*)(a12p + tok*64);
            float4 hi = *(const float4*)(a12p + tok*64 + 4);
            A0 = f4_fma(f1, lo.x, f4_fma(f2, lo.y, A0));
            A1 = f4_fma(f1, lo.z, f4_fma(f2, lo.w, A1));
            A2 = f4_fma(f1, hi.x, f4_fma(f2, hi.y, A2));
            A3 = f4_fma(f1, hi.z, f4_fma(f2, hi.w, A3));
        }
        *(float4*)(S + PO(gq*4+0, c)) = A0;
        *(float4*)(S + PO(gq*4+1, c)) = A1;
        *(float4*)(S + PO(gq*4+2, c)) = A2;
        *(float4*)(S + PO(gq*4+3, c)) = A3;
    } else if (tid < 24) {                 // SK/SV: 4 quads x 2
        int l = tid - 16, quad = l >> 1, c = l & 1;
        int isV = quad >> 1, d0 = (quad & 1) * 4;
        const float* tp = ws + (isV ? TVT : TKT) + d0;
        float4 A0 = make_float4(0,0,0,0), A1 = A0, A2 = A0, A3 = A0;
        #pragma unroll 4
        for (int i = 0; i < 48; ++i) {
            int tok = c*48 + i;
            float4 f1 = *(const float4*)(S + FO(tok));
            float4 w  = *(const float4*)(tp + tok*8);
            A0 = f4_fma(f1, w.x, A0); A1 = f4_fma(f1, w.y, A1);
            A2 = f4_fma(f1, w.z, A2); A3 = f4_fma(f1, w.w, A3);
        }
        int e0 = 32 + isV*8 + d0;
        *(float4*)(S + PO(e0+0, c)) = A0;
        *(float4*)(S + PO(e0+1, c)) = A1;
        *(float4*)(S + PO(e0+2, c)) = A2;
        *(float4*)(S + PO(e0+3, c)) = A3;
    } else if (tid < 40) {                 // d1: 8 quads x 2
        int l = tid - 24, dq = l >> 1, c = l & 1;
        const float* tp = ws + TD1 + 4*dq;
        float4 A0 = make_float4(0,0,0,0), A1 = A0, A2 = A0, A3 = A0;
        #pragma unroll 4
        for (int i = 0; i < 48; ++i) {
            int tok = c*48 + i;
            float4 f1 = *(const float4*)(S + FO(tok));
            float4 w  = *(const float4*)(tp + tok*32);
            A0 = f4_fma(f1, w.x, A0); A1 = f4_fma(f1, w.y, A1);
            A2 = f4_fma(f1, w.z, A2); A3 = f4_fma(f1, w.w, A3);
        }
        int e0 = 48 + dq*4;
        *(float4*)(S + PO(e0+0, c)) = A0;
        *(float4*)(S + PO(e0+1, c)) = A1;
        *(float4*)(S + PO(e0+2, c)) = A2;
        *(float4*)(S + PO(e0+3, c)) = A3;
    }
    __syncthreads();

    // ---- P4b: combine partials + consts (80 tasks) ----
    if (tid < 80) {
        float4 a = *(const float4*)(S + PO(tid, 0));
        float4 b = *(const float4*)(S + PO(tid, 1));
        float cst;
        if (tid < 32)      cst = ws[A0T + tid];
        else if (tid < 40) cst = ws[SBK + tid - 32];
        else if (tid < 48) cst = ws[SBV + tid - 40];
        else               cst = ws[CD1 + tid - 48];
        float4 r = make_float4(a.x+b.x+cst, a.y+b.y+cst, a.z+b.z+cst, a.w+b.w+cst);
        if (tid >= 48) r = f4_relu(r);
        *(float4*)(S + SO(tid)) = r;
    }
    __syncthreads();

    // ---- P5: attention rows (3/thread, fixed h) + dnn2, fused head ----
    const int s  = tid & 3;
    const int h  = (tid >> 2) & 1;
    const int qb = tid >> 3;    // 0..31
    float Gr[16], SKr[4], SVr[4];
    #pragma unroll
    for (int i = 0; i < 16; ++i) Gr[i] = S[SO(h*16 + i) + s];
    #pragma unroll
    for (int i = 0; i < 4; ++i) {
        SKr[i] = S[SO(32 + h*4 + i) + s];
        SVr[i] = S[SO(40 + h*4 + i) + s];
    }

    float hd = 0.f;
    const float* rtb = ws + RT + h*1920;

    #pragma unroll
    for (int j = 0; j < 3; ++j) {
        int q = qb + 32*j;
        const float* rt = rtb + q*20;
        float4 rt0 = *(const float4*)(rt);
        float4 rt1 = *(const float4*)(rt+4);
        float4 rt2 = *(const float4*)(rt+8);
        float4 rt3 = *(const float4*)(rt+12);
        float4 rt4 = *(const float4*)(rt+16);
        float fq = S[FO(q) + s];
        float q0 = fmaf(fq, rt0.x, rt1.x), q1 = fmaf(fq, rt0.y, rt1.y);
        float q2 = fmaf(fq, rt0.z, rt1.z), q3 = fmaf(fq, rt0.w, rt1.w);
        float den = 96.f;
        den = fmaf(q0, SKr[0], den); den = fmaf(q1, SKr[1], den);
        den = fmaf(q2, SKr[2], den); den = fmaf(q3, SKr[3], den);
        float n0 = SVr[0], n1 = SVr[1], n2 = SVr[2], n3 = SVr[3];
        n0 = fmaf(q0, Gr[ 0], n0); n1 = fmaf(q0, Gr[ 1], n1);
        n2 = fmaf(q0, Gr[ 2], n2); n3 = fmaf(q0, Gr[ 3], n3);
        n0 = fmaf(q1, Gr[ 4], n0); n1 = fmaf(q1, Gr[ 5], n1);
        n2 = fmaf(q1, Gr[ 6], n2); n3 = fmaf(q1, Gr[ 7], n3);
        n0 = fmaf(q2, Gr[ 8], n0); n1 = fmaf(q2, Gr[ 9], n1);
        n2 = fmaf(q2, Gr[10], n2); n3 = fmaf(q2, Gr[11], n3);
        n0 = fmaf(q3, Gr[12], n0); n1 = fmaf(q3, Gr[13], n1);
        n2 = fmaf(q3, Gr[14], n2); n3 = fmaf(q3, Gr[15], n3);
        float rc = __builtin_amdgcn_rcpf(den);
        float a0 = fmaxf(fmaf(n0, rc, fmaf(fq, rt2.x, rt3.x)), 0.f);
        float a1 = fmaxf(fmaf(n1, rc, fmaf(fq, rt2.y, rt3.y)), 0.f);
        float a2 = fmaxf(fmaf(n2, rc, fmaf(fq, rt2.z, rt3.z)), 0.f);
        float a3 = fmaxf(fmaf(n3, rc, fmaf(fq, rt2.w, rt3.w)), 0.f);
        hd = fmaf(a0, rt4.x, hd); hd = fmaf(a1, rt4.y, hd);
        hd = fmaf(a2, rt4.z, hd); hd = fmaf(a3, rt4.w, hd);
    }

    if (tid < 64) {                        // dnn2: o = tid>>2, s = tid&3
        int o = tid >> 2;
        float acc = bd2[o];
        const float* wp = ws + WD2T + o*32;
        #pragma unroll
        for (int k4 = 0; k4 < 8; ++k4) {
            float4 w = *(const float4*)(wp + k4*4);
            acc = fmaf(S[SO(48 + k4*4 + 0) + s], w.x, acc);
            acc = fmaf(S[SO(48 + k4*4 + 1) + s], w.y, acc);
            acc = fmaf(S[SO(48 + k4*4 + 2) + s], w.z, acc);
            acc = fmaf(S[SO(48 + k4*4 + 3) + s], w.w, acc);
        }
        hd = fmaf(fmaxf(acc, 0.f), Wo[o], hd);
    }

    // reduce over lanes with same s (bits 2..5 of lane)
    hd += __shfl_xor(hd, 4);
    hd += __shfl_xor(hd, 8);
    hd += __shfl_xor(hd, 16);
    hd += __shfl_xor(hd, 32);
    if (lane < 4) S[RO + wv*4 + lane] = hd;
    __syncthreads();
    if (tid < 4) {
        float z = S[RO+tid] + S[RO+4+tid] + S[RO+8+tid] + S[RO+12+tid] + bo[0];
        out[blk*4 + tid] = 1.f / (1.f + __expf(-z));
    }
}

extern "C" void kernel_launch(void* const* d_in, const int* in_sizes, int n_in,
                              void* d_out, int out_size, void* d_ws, size_t ws_size,
                              hipStream_t stream) {
    const float* mod_fea = (const float*)d_in[0];
    const float* W1 = (const float*)d_in[1];
    const float* b1 = (const float*)d_in[2];
    const float* W2 = (const float*)d_in[3];
    const float* b2 = (const float*)d_in[4];
    const float* W3 = (const float*)d_in[5];
    const float* b3 = (const float*)d_in[6];
    const float* We = (const float*)d_in[7];
    const float* be = (const float*)d_in[8];
    const float* Wd1 = (const float*)d_in[9];
    const float* bd1 = (const float*)d_in[10];
    const float* Wd2 = (const float*)d_in[11];
    const float* bd2 = (const float*)d_in[12];
    const float* Wq = (const float*)d_in[13];
    const float* Wk = (const float*)d_in[14];
    const float* Wv = (const float*)d_in[15];
    const float* Wo = (const float*)d_in[16];
    const float* bo = (const float*)d_in[17];
    float* ws  = (float*)d_ws;
    float* out = (float*)d_out;

    hipLaunchKernelGGL(table_kernel, dim3(50), dim3(256), 0, stream,
                       We, be, Wq, Wk, Wv, Wd1, bd1, Wo, Wd2, ws);
    hipLaunchKernelGGL(autoint_kernel, dim3(NBLK), dim3(256), 0, stream,
                       mod_fea, W1, b1, W2, b2, W3, b3,
                       bd2, Wo, bo, ws, out);
}

// Round 8
// 75.266 us; speedup vs baseline: 1.3680x; 1.3680x over previous
//
#include <hip/hip_runtime.h>
#include <math.h>

#define BATCH 16384
#define NS 4
#define NBLK (BATCH/NS)  // 4096

// ---- ws float offsets ----
#define RT    0        // [192][20] {TQ4,BQ4,We4,be4,Wo4} (TQ/BQ pre-scaled 0.5)
#define A12   3840     // [96][32][2] {A1,A2}
#define TD1   9984     // [96][32]
#define TKT   13056    // [96][8]
#define TVT   13824    // [96][8]
#define A0T   14592    // [32]
#define CD1   14624    // [32]
#define SBK   14656    // [8]
#define SBV   14664    // [8]
#define WD2T  14672    // [16][32]

__device__ __forceinline__ float4 f4_fma(float4 a, float s, float4 c) {
    return make_float4(fmaf(a.x,s,c.x), fmaf(a.y,s,c.y), fmaf(a.z,s,c.z), fmaf(a.w,s,c.w));
}
__device__ __forceinline__ float4 f4_relu(float4 a) {
    return make_float4(fmaxf(a.x,0.f),fmaxf(a.y,0.f),fmaxf(a.z,0.f),fmaxf(a.w,0.f));
}
__device__ __forceinline__ float4 f4_adds(float4 a, float s) {
    return make_float4(a.x+s, a.y+s, a.z+s, a.w+s);
}
__device__ __forceinline__ float4 f4_add(float4 a, float4 b) {
    return make_float4(a.x+b.x, a.y+b.y, a.z+b.z, a.w+b.w);
}
__device__ __forceinline__ void f4_redxor(float4& a, int m) {
    a.x += __shfl_xor(a.x, m); a.y += __shfl_xor(a.y, m);
    a.z += __shfl_xor(a.z, m); a.w += __shfl_xor(a.w, m);
}

// ---------------- table kernel (fully parallel/chunked) ----------------
__global__ __launch_bounds__(256) void table_kernel(
    const float* __restrict__ We, const float* __restrict__ be,
    const float* __restrict__ Wq, const float* __restrict__ Wk,
    const float* __restrict__ Wv, const float* __restrict__ Wd1,
    const float* __restrict__ bd1, const float* __restrict__ Wo,
    const float* __restrict__ Wd2,
    float* __restrict__ ws)
{
    int t = blockIdx.x * 256 + threadIdx.x;
    if (t < 3840) {                       // ROWTAB
        int r = t / 20, c = t % 20;
        int h = r / 96, q = r % 96;
        float v;
        if (c < 4) {
            float a = 0.f;
            #pragma unroll
            for (int i = 0; i < 8; ++i) a += We[q*8+i] * Wq[i*8 + h*4 + c];
            v = 0.5f * a;
        } else if (c < 8) {
            float a = 0.f;
            #pragma unroll
            for (int i = 0; i < 8; ++i) a += be[q*8+i] * Wq[i*8 + h*4 + (c-4)];
            v = 0.5f * a;
        } else if (c < 12) {
            v = We[q*8 + h*4 + (c-8)];
        } else if (c < 16) {
            v = be[q*8 + h*4 + (c-12)];
        } else {
            v = Wo[16 + q*8 + h*4 + (c-16)];
        }
        ws[RT + t] = v;
    } else if (t < 6912) {                // A12 [tok][g][2]
        int l = t - 3840, tok = l >> 5, g = l & 31;
        int h = g >> 4, d = (g >> 2) & 3, e = g & 3;
        float tk = 0.f, bk = 0.f, tv = 0.f, bv = 0.f;
        #pragma unroll
        for (int j = 0; j < 8; ++j) {
            float we = We[tok*8+j], b = be[tok*8+j];
            tk += we * Wk[j*8 + h*4 + d]; bk += b * Wk[j*8 + h*4 + d];
            tv += we * Wv[j*8 + h*4 + e]; bv += b * Wv[j*8 + h*4 + e];
        }
        ws[A12 + l*2]     = tk*bv + bk*tv;
        ws[A12 + l*2 + 1] = tk*tv;
    } else if (t < 9984) {                // TD1 [tok][32]
        int l = t - 6912, tok = l >> 5, g = l & 31;
        float a = 0.f;
        #pragma unroll
        for (int j = 0; j < 8; ++j) a += We[tok*8+j] * Wd1[(tok*8+j)*32 + g];
        ws[TD1 + l] = a;
    } else if (t < 11520) {               // TKT/TVT [tok][8]
        int l = t - 9984;
        int isV = l / 768, rem = l % 768;
        int tok = rem >> 3, d = rem & 7;
        const float* W = isV ? Wv : Wk;
        float a = 0.f;
        #pragma unroll
        for (int j = 0; j < 8; ++j) a += We[tok*8+j] * W[j*8 + d];
        ws[(isV ? TVT : TKT) + rem] = a;
    } else if (t < 11776) {               // A0T
        int l = t - 11520, g = l >> 3, c = l & 7;
        int h = g >> 4, d = (g >> 2) & 3, e = g & 3;
        float acc = 0.f;
        for (int tok = c*12; tok < c*12 + 12; ++tok) {
            float bk = 0.f, bv = 0.f;
            #pragma unroll
            for (int j = 0; j < 8; ++j) {
                float b = be[tok*8+j];
                bk += b * Wk[j*8 + h*4 + d];
                bv += b * Wv[j*8 + h*4 + e];
            }
            acc += bk * bv;
        }
        acc += __shfl_xor(acc,1); acc += __shfl_xor(acc,2); acc += __shfl_xor(acc,4);
        if (c == 0) ws[A0T + g] = acc;
    } else if (t < 12032) {               // CD1
        int l = t - 11776, g = l >> 3, c = l & 7;
        float acc = 0.f;
        for (int i = c*96; i < c*96 + 96; ++i) acc += be[i] * Wd1[i*32 + g];
        acc += __shfl_xor(acc,1); acc += __shfl_xor(acc,2); acc += __shfl_xor(acc,4);
        if (c == 0) ws[CD1 + g] = acc + bd1[g];
    } else if (t < 12288) {               // SBK/SBV
        int l = t - 12032, idx = l >> 4, c = l & 15;
        int isV = idx >> 3, d = idx & 7;
        const float* W = isV ? Wv : Wk;
        float acc = 0.f;
        for (int i = c*48; i < c*48 + 48; ++i) acc += be[i] * W[(i & 7)*8 + d];
        acc += __shfl_xor(acc,1); acc += __shfl_xor(acc,2);
        acc += __shfl_xor(acc,4); acc += __shfl_xor(acc,8);
        if (c == 0) ws[(isV ? SBV : SBK) + d] = acc;
    } else if (t < 12800) {               // WD2T [16][32]
        int l = t - 12288, o = l >> 5, k = l & 31;
        ws[WD2T + l] = Wd2[k*16 + o];
    }
}

// ---------------- main kernel: R3 structure + weight-column prefetch ----------------
__global__ __launch_bounds__(256) void autoint_kernel(
    const float* __restrict__ mod_fea,
    const float* __restrict__ W1, const float* __restrict__ b1,
    const float* __restrict__ W2, const float* __restrict__ b2,
    const float* __restrict__ W3, const float* __restrict__ b3,
    const float* __restrict__ bd2,
    const float* __restrict__ Wo, const float* __restrict__ bo,
    const float* __restrict__ ws,
    float* __restrict__ out)
{
    const int tid  = threadIdx.x;
    const int blk  = blockIdx.x;
    const int lane = tid & 63;
    const int wv   = tid >> 6;

    __shared__ __align__(16) float s_reg[2496];   // h1[0..1536) | xT->h2T [1536..2496)
    __shared__ __align__(16) float s_flat[384];   // [96][4]
    __shared__ __align__(16) float s_flat2[384];
    __shared__ __align__(16) float s_G[128];      // [32][4]
    __shared__ __align__(16) float s_SK[32];      // [8][4]
    __shared__ __align__(16) float s_SV[32];
    __shared__ __align__(16) float s_d1[128];     // [32][4]
    __shared__ float s_red[16];

    // ---- P0: load 4 rows, transpose xT[f][s] at s_reg+1536 ----
    for (int idx = tid; idx < 960; idx += 256) {
        int s = idx / 240, f = idx - s*240;
        s_reg[1536 + f*4 + s] = mod_fea[(size_t)blk*960 + idx];
    }
    __syncthreads();

    // ---- P1: h1 = relu(x@W1+b1), 384 outputs; weight column in regs ----
    for (int idx = tid; idx < 384; idx += 256) {
        int m = idx >> 6, oo = idx & 63;
        const float* wp = W1 + m*2560 + oo;
        float w[40];
        #pragma unroll
        for (int f = 0; f < 40; ++f) w[f] = wp[f*64];
        float bb = b1[idx];
        float4 accA = make_float4(bb,bb,bb,bb), accB = make_float4(0,0,0,0);
        const float* xp = s_reg + 1536 + m*160;
        #pragma unroll
        for (int f = 0; f < 40; f += 2) {
            accA = f4_fma(*(const float4*)(xp + f*4),     w[f],   accA);
            accB = f4_fma(*(const float4*)(xp + f*4 + 4), w[f+1], accB);
        }
        *(float4*)(s_reg + idx*4) = f4_relu(f4_add(accA, accB));
    }
    __syncthreads();

    // ---- P2: h2 at s_reg+1536, 192 outputs ----
    if (tid < 192) {
        int m = tid >> 5, oo = tid & 31;
        const float* wp = W2 + m*2048 + oo;
        float w[64];
        #pragma unroll
        for (int k = 0; k < 64; ++k) w[k] = wp[k*32];
        float bb = b2[tid];
        float4 accA = make_float4(bb,bb,bb,bb), accB = make_float4(0,0,0,0);
        const float* hp = s_reg + m*256;
        #pragma unroll
        for (int k = 0; k < 64; k += 2) {
            accA = f4_fma(*(const float4*)(hp + k*4),     w[k],   accA);
            accB = f4_fma(*(const float4*)(hp + k*4 + 4), w[k+1], accB);
        }
        *(float4*)(s_reg + 1536 + tid*4) = f4_relu(f4_add(accA, accB));
    }
    __syncthreads();

    // ---- P3: flat + flat^2, 96 outputs ----
    if (tid < 96) {
        int m = tid >> 4, oo = tid & 15;
        const float* wp = W3 + m*512 + oo;
        float w[32];
        #pragma unroll
        for (int k = 0; k < 32; ++k) w[k] = wp[k*16];
        float bb = b3[tid];
        float4 accA = make_float4(bb,bb,bb,bb), accB = make_float4(0,0,0,0);
        const float* hp = s_reg + 1536 + m*128;
        #pragma unroll
        for (int k = 0; k < 32; k += 2) {
            accA = f4_fma(*(const float4*)(hp + k*4),     w[k],   accA);
            accB = f4_fma(*(const float4*)(hp + k*4 + 4), w[k+1], accB);
        }
        float4 r = f4_relu(f4_add(accA, accB));
        *(float4*)(s_flat + tid*4) = r;
        *(float4*)(s_flat2 + tid*4) = make_float4(r.x*r.x, r.y*r.y, r.z*r.z, r.w*r.w);
    }
    __syncthreads();

    // ---- P4: per-sample stats: G[32], SK[8], SV[8], dnn1[32] ----
    if (tid < 128) {                 // G: 32 g x 4 chunks
        int g = tid >> 2, c = tid & 3;
        float4 acc = make_float4(0,0,0,0);
        #pragma unroll 4
        for (int i = 0; i < 24; ++i) {
            int tok = i*4 + c;
            float2 a12 = *(const float2*)(ws + A12 + (tok*32 + g)*2);
            float4 f1 = *(const float4*)(s_flat  + tok*4);
            float4 f2 = *(const float4*)(s_flat2 + tok*4);
            acc = f4_fma(f2, a12.y, f4_fma(f1, a12.x, acc));
        }
        f4_redxor(acc, 1); f4_redxor(acc, 2);
        if (c == 0) *(float4*)(s_G + g*4) = f4_adds(acc, ws[A0T + g]);
    } else if (tid < 192) {          // SK/SV: 2 x 8 d x 4 chunks
        int l = tid - 128, isV = l >> 5, d = (l >> 2) & 7, c = l & 3;
        const float* tp = ws + (isV ? TVT : TKT);
        float4 acc = make_float4(0,0,0,0);
        #pragma unroll 4
        for (int i = 0; i < 24; ++i) {
            int tok = i*4 + c;
            acc = f4_fma(*(const float4*)(s_flat + tok*4), tp[tok*8 + d], acc);
        }
        f4_redxor(acc, 1); f4_redxor(acc, 2);
        if (c == 0) {
            float sb = ws[(isV ? SBV : SBK) + d];
            *(float4*)((isV ? s_SV : s_SK) + d*4) = f4_adds(acc, sb);
        }
    } else {                         // d1: 32 g x 2 chunks
        int l = tid - 192, g = l >> 1, c = l & 1;
        float4 acc = make_float4(0,0,0,0);
        #pragma unroll 4
        for (int i = 0; i < 48; ++i) {
            int tok = i*2 + c;
            acc = f4_fma(*(const float4*)(s_flat + tok*4), ws[TD1 + tok*32 + g], acc);
        }
        f4_redxor(acc, 1);
        if (c == 0) *(float4*)(s_d1 + g*4) = f4_relu(f4_adds(acc, ws[CD1 + g]));
    }
    __syncthreads();

    // ---- P5: attention rows (3/thread, stats in regs) + dnn2, fused head ----
    const int s  = tid & 3;
    const int h  = (tid >> 2) & 1;
    const int qb = tid >> 3;    // 0..31
    float Gr[16], SKr[4], SVr[4];
    #pragma unroll
    for (int i = 0; i < 16; ++i) Gr[i] = s_G[(h*16 + i)*4 + s];
    #pragma unroll
    for (int i = 0; i < 4; ++i) {
        SKr[i] = s_SK[(h*4 + i)*4 + s];
        SVr[i] = s_SV[(h*4 + i)*4 + s];
    }

    float hd = 0.f;
    const float* rtb = ws + RT + h*1920;

    #pragma unroll
    for (int j = 0; j < 3; ++j) {
        int q = qb + 32*j;
        const float* rt = rtb + q*20;
        float4 rt0 = *(const float4*)(rt);
        float4 rt1 = *(const float4*)(rt+4);
        float4 rt2 = *(const float4*)(rt+8);
        float4 rt3 = *(const float4*)(rt+12);
        float4 rt4 = *(const float4*)(rt+16);
        float fq = s_flat[q*4 + s];
        float q0 = fmaf(fq, rt0.x, rt1.x), q1 = fmaf(fq, rt0.y, rt1.y);
        float q2 = fmaf(fq, rt0.z, rt1.z), q3 = fmaf(fq, rt0.w, rt1.w);
        float den = 96.f;
        den = fmaf(q0, SKr[0], den); den = fmaf(q1, SKr[1], den);
        den = fmaf(q2, SKr[2], den); den = fmaf(q3, SKr[3], den);
        float n0 = SVr[0], n1 = SVr[1], n2 = SVr[2], n3 = SVr[3];
        n0 = fmaf(q0, Gr[ 0], n0); n1 = fmaf(q0, Gr[ 1], n1);
        n2 = fmaf(q0, Gr[ 2], n2); n3 = fmaf(q0, Gr[ 3], n3);
        n0 = fmaf(q1, Gr[ 4], n0); n1 = fmaf(q1, Gr[ 5], n1);
        n2 = fmaf(q1, Gr[ 6], n2); n3 = fmaf(q1, Gr[ 7], n3);
        n0 = fmaf(q2, Gr[ 8], n0); n1 = fmaf(q2, Gr[ 9], n1);
        n2 = fmaf(q2, Gr[10], n2); n3 = fmaf(q2, Gr[11], n3);
        n0 = fmaf(q3, Gr[12], n0); n1 = fmaf(q3, Gr[13], n1);
        n2 = fmaf(q3, Gr[14], n2); n3 = fmaf(q3, Gr[15], n3);
        float rc = __builtin_amdgcn_rcpf(den);
        float a0 = fmaxf(fmaf(n0, rc, fmaf(fq, rt2.x, rt3.x)), 0.f);
        float a1 = fmaxf(fmaf(n1, rc, fmaf(fq, rt2.y, rt3.y)), 0.f);
        float a2 = fmaxf(fmaf(n2, rc, fmaf(fq, rt2.z, rt3.z)), 0.f);
        float a3 = fmaxf(fmaf(n3, rc, fmaf(fq, rt2.w, rt3.w)), 0.f);
        hd = fmaf(a0, rt4.x, hd); hd = fmaf(a1, rt4.y, hd);
        hd = fmaf(a2, rt4.z, hd); hd = fmaf(a3, rt4.w, hd);
    }

    if (tid < 64) {                        // dnn2: o = tid>>2, sample = tid&3
        int o = tid >> 2;
        float acc = bd2[o];
        const float* wp = ws + WD2T + o*32;
        #pragma unroll
        for (int k4 = 0; k4 < 8; ++k4) {
            float4 w = *(const float4*)(wp + k4*4);
            acc = fmaf(s_d1[(k4*4+0)*4 + s], w.x, acc);
            acc = fmaf(s_d1[(k4*4+1)*4 + s], w.y, acc);
            acc = fmaf(s_d1[(k4*4+2)*4 + s], w.z, acc);
            acc = fmaf(s_d1[(k4*4+3)*4 + s], w.w, acc);
        }
        hd = fmaf(fmaxf(acc, 0.f), Wo[o], hd);
    }

    hd += __shfl_xor(hd, 4);
    hd += __shfl_xor(hd, 8);
    hd += __shfl_xor(hd, 16);
    hd += __shfl_xor(hd, 32);
    if (lane < 4) s_red[wv*4 + lane] = hd;
    __syncthreads();
    if (tid < 4) {
        float z = s_red[tid] + s_red[4+tid] + s_red[8+tid] + s_red[12+tid] + bo[0];
        out[blk*4 + tid] = 1.f / (1.f + __expf(-z));
    }
}

extern "C" void kernel_launch(void* const* d_in, const int* in_sizes, int n_in,
                              void* d_out, int out_size, void* d_ws, size_t ws_size,
                              hipStream_t stream) {
    const float* mod_fea = (const float*)d_in[0];
    const float* W1 = (const float*)d_in[1];
    const float* b1 = (const float*)d_in[2];
    const float* W2 = (const float*)d_in[3];
    const float* b2 = (const float*)d_in[4];
    const float* W3 = (const float*)d_in[5];
    const float* b3 = (const float*)d_in[6];
    const float* We = (const float*)d_in[7];
    const float* be = (const float*)d_in[8];
    const float* Wd1 = (const float*)d_in[9];
    const float* bd1 = (const float*)d_in[10];
    const float* Wd2 = (const float*)d_in[11];
    const float* bd2 = (const float*)d_in[12];
    const float* Wq = (const float*)d_in[13];
    const float* Wk = (const float*)d_in[14];
    const float* Wv = (const float*)d_in[15];
    const float* Wo = (const float*)d_in[16];
    const float* bo = (const float*)d_in[17];
    float* ws  = (float*)d_ws;
    float* out = (float*)d_out;

    hipLaunchKernelGGL(table_kernel, dim3(50), dim3(256), 0, stream,
                       We, be, Wq, Wk, Wv, Wd1, bd1, Wo, Wd2, ws);
    hipLaunchKernelGGL(autoint_kernel, dim3(NBLK), dim3(256), 0, stream,
                       mod_fea, W1, b1, W2, b2, W3, b3,
                       bd2, Wo, bo, ws, out);
}

// Round 9
// 33.352 us; speedup vs baseline: 3.0872x; 2.2567x over previous
//
#include <hip/hip_runtime.h>
#include <math.h>

#define BATCH 16384

// ---- ws float offsets ----
#define RT    0        // [192][20] {TQ4,BQ4,We4,be4,Wo4}  (TQ/BQ pre-scaled 0.5)
#define A0T   3840     // [32]
#define CD1   3872     // [32]
#define SBKV  3904     // [16]  0-7 SK const, 8-15 SV const
#define WD2T  3920     // [16][32]
#define FB    4432     // fragment files: 99 frags x 64 lanes x 4 dwords (bf16-packed)
// frag ids: W1F: m*8+kt*4+ot (0..47) | W2F: 48+m*4+kt*2+ot (48..71) | W3F: 72+m (72..77)
//           AGF: 78+kt*2+ot (78..89) | ADF: 90+kt*2+ot (90..95)    | ASF: 96+kt (96..98)

typedef __attribute__((ext_vector_type(8))) short short8;
typedef __attribute__((ext_vector_type(4))) float f32x4;

union FRAG { int4 i; short8 s; };

__device__ __forceinline__ unsigned pkbf(float a, float b) {
    unsigned ua = __float_as_uint(a); ua += 0x7FFFu + ((ua >> 16) & 1u);
    unsigned ub = __float_as_uint(b); ub += 0x7FFFu + ((ub >> 16) & 1u);
    return (ua >> 16) | (ub & 0xFFFF0000u);
}

#define MFMA(A, B, C) __builtin_amdgcn_mfma_f32_16x16x32_bf16((A), (B), (C), 0, 0, 0)

// ---------------- table kernel ----------------
__global__ __launch_bounds__(256) void table_kernel(
    const float* __restrict__ We, const float* __restrict__ be,
    const float* __restrict__ Wq, const float* __restrict__ Wk,
    const float* __restrict__ Wv, const float* __restrict__ Wd1,
    const float* __restrict__ bd1, const float* __restrict__ Wo,
    const float* __restrict__ Wd2,
    const float* __restrict__ W1, const float* __restrict__ W2,
    const float* __restrict__ W3,
    float* __restrict__ ws)
{
    int t = blockIdx.x * 256 + threadIdx.x;
    if (t < 3840) {                              // ROWTAB
        int r = t / 20, c = t % 20;
        int h = r / 96, q = r % 96;
        float v;
        if (c < 4) {
            float a = 0.f;
            #pragma unroll
            for (int i = 0; i < 8; ++i) a += We[q*8+i] * Wq[i*8 + h*4 + c];
            v = 0.5f * a;
        } else if (c < 8) {
            float a = 0.f;
            #pragma unroll
            for (int i = 0; i < 8; ++i) a += be[q*8+i] * Wq[i*8 + h*4 + (c-4)];
            v = 0.5f * a;
        } else if (c < 12) {
            v = We[q*8 + h*4 + (c-8)];
        } else if (c < 16) {
            v = be[q*8 + h*4 + (c-12)];
        } else {
            v = Wo[16 + q*8 + h*4 + (c-16)];
        }
        ws[RT + t] = v;
    } else if (t < 4096) {                       // A0T: 32 g x 8 chunks
        int l = t - 3840, g = l >> 3, c = l & 7;
        int h = g >> 4, d = (g >> 2) & 3, e = g & 3;
        float acc = 0.f;
        for (int tok = c*12; tok < c*12 + 12; ++tok) {
            float bk = 0.f, bv = 0.f;
            #pragma unroll
            for (int j = 0; j < 8; ++j) {
                float b = be[tok*8+j];
                bk += b * Wk[j*8 + h*4 + d];
                bv += b * Wv[j*8 + h*4 + e];
            }
            acc += bk * bv;
        }
        acc += __shfl_xor(acc,1); acc += __shfl_xor(acc,2); acc += __shfl_xor(acc,4);
        if (c == 0) ws[A0T + g] = acc;
    } else if (t < 4352) {                       // CD1: 32 g x 8 chunks
        int l = t - 4096, g = l >> 3, c = l & 7;
        float acc = 0.f;
        for (int i = c*96; i < c*96 + 96; ++i) acc += be[i] * Wd1[i*32 + g];
        acc += __shfl_xor(acc,1); acc += __shfl_xor(acc,2); acc += __shfl_xor(acc,4);
        if (c == 0) ws[CD1 + g] = acc + bd1[g];
    } else if (t < 4608) {                       // SBKV: 16 x 16 chunks
        int l = t - 4352, idx = l >> 4, c = l & 15;
        int isV = idx >> 3, d = idx & 7;
        const float* W = isV ? Wv : Wk;
        float acc = 0.f;
        for (int i = c*48; i < c*48 + 48; ++i) acc += be[i] * W[(i & 7)*8 + d];
        acc += __shfl_xor(acc,1); acc += __shfl_xor(acc,2);
        acc += __shfl_xor(acc,4); acc += __shfl_xor(acc,8);
        if (c == 0) ws[SBKV + idx] = acc;
    } else if (t < 5120) {                       // WD2T [16][32]
        int l = t - 4608, o = l >> 5, k = l & 31;
        ws[WD2T + l] = Wd2[k*16 + o];
    } else if (t < 11456) {                      // fragment files
        int l = t - 5120, fi = l >> 6, lane = l & 63;
        int g = lane >> 4, c = lane & 15;
        float v[8];
        if (fi < 48) {                           // W1F
            int m = fi >> 3, kt = (fi >> 2) & 1, ot = fi & 3;
            #pragma unroll
            for (int j = 0; j < 8; ++j) {
                int k = kt*32 + g*8 + j;
                v[j] = (k < 40) ? W1[(m*40 + k)*64 + ot*16 + c] : 0.f;
            }
        } else if (fi < 72) {                    // W2F
            int x = fi - 48, m = x >> 2, kt = (x >> 1) & 1, ot = x & 1;
            #pragma unroll
            for (int j = 0; j < 8; ++j) {
                int k = kt*32 + g*8 + j;
                v[j] = W2[(m*64 + k)*32 + ot*16 + c];
            }
        } else if (fi < 78) {                    // W3F
            int m = fi - 72;
            #pragma unroll
            for (int j = 0; j < 8; ++j)
                v[j] = W3[(m*32 + g*8 + j)*16 + c];
        } else if (fi < 90) {                    // AGF: rows g-idx, K=[flat|flat2]
            int x = fi - 78, kt = x >> 1, ot = x & 1, row = ot*16 + c;
            int hh = row >> 4, d = (row >> 2) & 3, e = row & 3;
            #pragma unroll
            for (int j = 0; j < 8; ++j) {
                int k = kt*32 + g*8 + j;
                int tok = (k < 96) ? k : (k - 96);
                float tk = 0.f, bk = 0.f, tv = 0.f, bv = 0.f;
                #pragma unroll
                for (int j8 = 0; j8 < 8; ++j8) {
                    float we = We[tok*8+j8], b = be[tok*8+j8];
                    tk += we * Wk[j8*8 + hh*4 + d]; bk += b * Wk[j8*8 + hh*4 + d];
                    tv += we * Wv[j8*8 + hh*4 + e]; bv += b * Wv[j8*8 + hh*4 + e];
                }
                v[j] = (k < 96) ? (tk*bv + bk*tv) : (tk*tv);
            }
        } else if (fi < 96) {                    // ADF: rows dnn1-g, K=flat
            int x = fi - 90, kt = x >> 1, ot = x & 1, row = ot*16 + c;
            #pragma unroll
            for (int j = 0; j < 8; ++j) {
                int tok = kt*32 + g*8 + j;
                float a = 0.f;
                #pragma unroll
                for (int j8 = 0; j8 < 8; ++j8)
                    a += We[tok*8+j8] * Wd1[(tok*8+j8)*32 + row];
                v[j] = a;
            }
        } else {                                 // ASF: rows 0-7 SK, 8-15 SV
            int kt = fi - 96, row = c, d = row & 7;
            const float* W = (row < 8) ? Wk : Wv;
            #pragma unroll
            for (int j = 0; j < 8; ++j) {
                int tok = kt*32 + g*8 + j;
                float a = 0.f;
                #pragma unroll
                for (int j8 = 0; j8 < 8; ++j8)
                    a += We[tok*8+j8] * W[j8*8 + d];
                v[j] = a;
            }
        }
        float* dst = ws + FB + (fi*64 + lane)*4;
        dst[0] = __uint_as_float(pkbf(v[0], v[1]));
        dst[1] = __uint_as_float(pkbf(v[2], v[3]));
        dst[2] = __uint_as_float(pkbf(v[4], v[5]));
        dst[3] = __uint_as_float(pkbf(v[6], v[7]));
    }
}

// ---------------- main kernel: 1 wave / 16 samples per block, MFMA ----------------
__global__ __launch_bounds__(64) void autoint_kernel(
    const float* __restrict__ mod_fea,
    const float* __restrict__ b1, const float* __restrict__ b2,
    const float* __restrict__ b3, const float* __restrict__ bd2,
    const float* __restrict__ Wo, const float* __restrict__ bo,
    const float* __restrict__ ws,
    float* __restrict__ out)
{
    const int lane = threadIdx.x;        // 0..63
    const int g = lane >> 4, c = lane & 15;
    const int blk = blockIdx.x;

    __shared__ unsigned short h1buf[16*72];   // [s][64+pad] bf16
    __shared__ unsigned short h2buf[16*40];   // [s][32+pad]
    __shared__ unsigned short fbuf [16*200];  // [s][flat 96 | flat2 96 | pad]
    __shared__ float s_stat[80*17];           // [stat row][16 samples+pad]

    const int4* fragp = (const int4*)(ws + FB);
    const float* xrow = mod_fea + (size_t)(blk*16 + c)*240;

    // ================= stage A: 6 module MLP chains (MFMA) =================
    for (int m = 0; m < 6; ++m) {
        // B-frags of x: kt0 = k 0..31, kt1 = k 32..39 (zero-padded)
        FRAG bx0, bx1;
        {
            float4 f0 = *(const float4*)(xrow + m*40 + g*8);
            float4 f1 = *(const float4*)(xrow + m*40 + g*8 + 4);
            bx0.i = make_int4(pkbf(f0.x,f0.y), pkbf(f0.z,f0.w),
                              pkbf(f1.x,f1.y), pkbf(f1.z,f1.w));
        }
        if (g == 0) {
            float4 f0 = *(const float4*)(xrow + m*40 + 32);
            float4 f1 = *(const float4*)(xrow + m*40 + 36);
            bx1.i = make_int4(pkbf(f0.x,f0.y), pkbf(f0.z,f0.w),
                              pkbf(f1.x,f1.y), pkbf(f1.z,f1.w));
        } else {
            bx1.i = make_int4(0,0,0,0);
        }

        // ---- M1: h1[64][16] ----
        #pragma unroll
        for (int ot = 0; ot < 4; ++ot) {
            FRAG a0, a1;
            a0.i = fragp[(m*8 + 0*4 + ot)*64 + lane];
            a1.i = fragp[(m*8 + 1*4 + ot)*64 + lane];
            f32x4 acc = {0.f, 0.f, 0.f, 0.f};
            acc = MFMA(a0.s, bx0.s, acc);
            acc = MFMA(a1.s, bx1.s, acc);
            float4 bb = *(const float4*)(b1 + m*64 + ot*16 + g*4);
            float r0 = fmaxf(acc[0] + bb.x, 0.f);
            float r1 = fmaxf(acc[1] + bb.y, 0.f);
            float r2 = fmaxf(acc[2] + bb.z, 0.f);
            float r3 = fmaxf(acc[3] + bb.w, 0.f);
            *(uint2*)(&h1buf[c*72 + ot*16 + g*4]) = make_uint2(pkbf(r0,r1), pkbf(r2,r3));
        }

        // ---- M2: h2[32][16] ----
        FRAG bh0, bh1;
        bh0.i = *(const int4*)(&h1buf[c*72 + 0*32 + g*8]);
        bh1.i = *(const int4*)(&h1buf[c*72 + 1*32 + g*8]);
        #pragma unroll
        for (int ot = 0; ot < 2; ++ot) {
            FRAG a0, a1;
            a0.i = fragp[(48 + m*4 + 0*2 + ot)*64 + lane];
            a1.i = fragp[(48 + m*4 + 1*2 + ot)*64 + lane];
            f32x4 acc = {0.f, 0.f, 0.f, 0.f};
            acc = MFMA(a0.s, bh0.s, acc);
            acc = MFMA(a1.s, bh1.s, acc);
            float4 bb = *(const float4*)(b2 + m*32 + ot*16 + g*4);
            float r0 = fmaxf(acc[0] + bb.x, 0.f);
            float r1 = fmaxf(acc[1] + bb.y, 0.f);
            float r2 = fmaxf(acc[2] + bb.z, 0.f);
            float r3 = fmaxf(acc[3] + bb.w, 0.f);
            *(uint2*)(&h2buf[c*40 + ot*16 + g*4]) = make_uint2(pkbf(r0,r1), pkbf(r2,r3));
        }

        // ---- M3: flat[16][16] ----
        {
            FRAG bh2, a;
            bh2.i = *(const int4*)(&h2buf[c*40 + g*8]);
            a.i   = fragp[(72 + m)*64 + lane];
            f32x4 acc = {0.f, 0.f, 0.f, 0.f};
            acc = MFMA(a.s, bh2.s, acc);
            float4 bb = *(const float4*)(b3 + m*16 + g*4);
            float r0 = fmaxf(acc[0] + bb.x, 0.f);
            float r1 = fmaxf(acc[1] + bb.y, 0.f);
            float r2 = fmaxf(acc[2] + bb.z, 0.f);
            float r3 = fmaxf(acc[3] + bb.w, 0.f);
            *(uint2*)(&fbuf[c*200 + m*16 + g*4]) =
                make_uint2(pkbf(r0,r1), pkbf(r2,r3));
            *(uint2*)(&fbuf[c*200 + 96 + m*16 + g*4]) =
                make_uint2(pkbf(r0*r0, r1*r1), pkbf(r2*r2, r3*r3));
        }
    }

    // ================= P4: stats via MFMA =================
    {
        FRAG bf0, bf1, bf2, bf3, bf4, bf5;
        bf0.i = *(const int4*)(&fbuf[c*200 + 0*32 + g*8]);
        bf1.i = *(const int4*)(&fbuf[c*200 + 1*32 + g*8]);
        bf2.i = *(const int4*)(&fbuf[c*200 + 2*32 + g*8]);
        bf3.i = *(const int4*)(&fbuf[c*200 + 3*32 + g*8]);
        bf4.i = *(const int4*)(&fbuf[c*200 + 4*32 + g*8]);
        bf5.i = *(const int4*)(&fbuf[c*200 + 5*32 + g*8]);

        // G (rows 0..31)
        #pragma unroll
        for (int ot = 0; ot < 2; ++ot) {
            f32x4 acc = {0.f, 0.f, 0.f, 0.f};
            FRAG a;
            a.i = fragp[(78 + 0*2 + ot)*64 + lane]; acc = MFMA(a.s, bf0.s, acc);
            a.i = fragp[(78 + 1*2 + ot)*64 + lane]; acc = MFMA(a.s, bf1.s, acc);
            a.i = fragp[(78 + 2*2 + ot)*64 + lane]; acc = MFMA(a.s, bf2.s, acc);
            a.i = fragp[(78 + 3*2 + ot)*64 + lane]; acc = MFMA(a.s, bf3.s, acc);
            a.i = fragp[(78 + 4*2 + ot)*64 + lane]; acc = MFMA(a.s, bf4.s, acc);
            a.i = fragp[(78 + 5*2 + ot)*64 + lane]; acc = MFMA(a.s, bf5.s, acc);
            float4 a0 = *(const float4*)(ws + A0T + ot*16 + g*4);
            int row = ot*16 + g*4;
            s_stat[(row+0)*17 + c] = acc[0] + a0.x;
            s_stat[(row+1)*17 + c] = acc[1] + a0.y;
            s_stat[(row+2)*17 + c] = acc[2] + a0.z;
            s_stat[(row+3)*17 + c] = acc[3] + a0.w;
        }
        // SK/SV (rows 32..47)
        {
            f32x4 acc = {0.f, 0.f, 0.f, 0.f};
            FRAG a;
            a.i = fragp[(96 + 0)*64 + lane]; acc = MFMA(a.s, bf0.s, acc);
            a.i = fragp[(96 + 1)*64 + lane]; acc = MFMA(a.s, bf1.s, acc);
            a.i = fragp[(96 + 2)*64 + lane]; acc = MFMA(a.s, bf2.s, acc);
            float4 sb = *(const float4*)(ws + SBKV + g*4);
            int row = 32 + g*4;
            s_stat[(row+0)*17 + c] = acc[0] + sb.x;
            s_stat[(row+1)*17 + c] = acc[1] + sb.y;
            s_stat[(row+2)*17 + c] = acc[2] + sb.z;
            s_stat[(row+3)*17 + c] = acc[3] + sb.w;
        }
        // d1 (rows 48..79)
        #pragma unroll
        for (int ot = 0; ot < 2; ++ot) {
            f32x4 acc = {0.f, 0.f, 0.f, 0.f};
            FRAG a;
            a.i = fragp[(90 + 0*2 + ot)*64 + lane]; acc = MFMA(a.s, bf0.s, acc);
            a.i = fragp[(90 + 1*2 + ot)*64 + lane]; acc = MFMA(a.s, bf1.s, acc);
            a.i = fragp[(90 + 2*2 + ot)*64 + lane]; acc = MFMA(a.s, bf2.s, acc);
            float4 cd = *(const float4*)(ws + CD1 + ot*16 + g*4);
            int row = 48 + ot*16 + g*4;
            s_stat[(row+0)*17 + c] = fmaxf(acc[0] + cd.x, 0.f);
            s_stat[(row+1)*17 + c] = fmaxf(acc[1] + cd.y, 0.f);
            s_stat[(row+2)*17 + c] = fmaxf(acc[2] + cd.z, 0.f);
            s_stat[(row+3)*17 + c] = fmaxf(acc[3] + cd.w, 0.f);
        }
    }

    // ================= P5: attention rows + dnn2 + head =================
    const int s  = lane & 15;
    const int rg = lane >> 4;        // 0..3
    const int h  = rg >> 1;
    const int q0 = (rg & 1) * 48;

    float Gr[16], SKr[4], SVr[4];
    #pragma unroll
    for (int i = 0; i < 16; ++i) Gr[i] = s_stat[(h*16 + i)*17 + s];
    #pragma unroll
    for (int d = 0; d < 4; ++d) {
        SKr[d] = s_stat[(32 + h*4 + d)*17 + s];
        SVr[d] = s_stat[(40 + h*4 + d)*17 + s];
    }

    float hd = 0.f;
    const float* rtb = ws + RT + h*1920;

    #pragma unroll 4
    for (int q = q0; q < q0 + 48; ++q) {
        const float* rt = rtb + q*20;
        float4 rt0 = *(const float4*)(rt);
        float4 rt1 = *(const float4*)(rt+4);
        float4 rt2 = *(const float4*)(rt+8);
        float4 rt3 = *(const float4*)(rt+12);
        float4 rt4 = *(const float4*)(rt+16);
        float fq = __uint_as_float(((unsigned)fbuf[s*200 + q]) << 16);
        float qq0 = fmaf(fq, rt0.x, rt1.x), qq1 = fmaf(fq, rt0.y, rt1.y);
        float qq2 = fmaf(fq, rt0.z, rt1.z), qq3 = fmaf(fq, rt0.w, rt1.w);
        float den = 96.f;
        den = fmaf(qq0, SKr[0], den); den = fmaf(qq1, SKr[1], den);
        den = fmaf(qq2, SKr[2], den); den = fmaf(qq3, SKr[3], den);
        float n0 = SVr[0], n1 = SVr[1], n2 = SVr[2], n3 = SVr[3];
        n0 = fmaf(qq0, Gr[ 0], n0); n1 = fmaf(qq0, Gr[ 1], n1);
        n2 = fmaf(qq0, Gr[ 2], n2); n3 = fmaf(qq0, Gr[ 3], n3);
        n0 = fmaf(qq1, Gr[ 4], n0); n1 = fmaf(qq1, Gr[ 5], n1);
        n2 = fmaf(qq1, Gr[ 6], n2); n3 = fmaf(qq1, Gr[ 7], n3);
        n0 = fmaf(qq2, Gr[ 8], n0); n1 = fmaf(qq2, Gr[ 9], n1);
        n2 = fmaf(qq2, Gr[10], n2); n3 = fmaf(qq2, Gr[11], n3);
        n0 = fmaf(qq3, Gr[12], n0); n1 = fmaf(qq3, Gr[13], n1);
        n2 = fmaf(qq3, Gr[14], n2); n3 = fmaf(qq3, Gr[15], n3);
        float rc = __builtin_amdgcn_rcpf(den);
        float a0 = fmaxf(fmaf(n0, rc, fmaf(fq, rt2.x, rt3.x)), 0.f);
        float a1 = fmaxf(fmaf(n1, rc, fmaf(fq, rt2.y, rt3.y)), 0.f);
        float a2 = fmaxf(fmaf(n2, rc, fmaf(fq, rt2.z, rt3.z)), 0.f);
        float a3 = fmaxf(fmaf(n3, rc, fmaf(fq, rt2.w, rt3.w)), 0.f);
        hd = fmaf(a0, rt4.x, hd); hd = fmaf(a1, rt4.y, hd);
        hd = fmaf(a2, rt4.z, hd); hd = fmaf(a3, rt4.w, hd);
    }

    // dnn2: each thread computes 4 outputs o = rg*4..rg*4+3 for its sample
    {
        float d1r[32];
        #pragma unroll
        for (int k = 0; k < 32; ++k) d1r[k] = s_stat[(48 + k)*17 + s];
        #pragma unroll
        for (int jj = 0; jj < 4; ++jj) {
            int o = rg*4 + jj;
            float acc = bd2[o];
            const float* wp = ws + WD2T + o*32;
            #pragma unroll
            for (int k = 0; k < 32; ++k) acc = fmaf(d1r[k], wp[k], acc);
            hd = fmaf(fmaxf(acc, 0.f), Wo[o], hd);
        }
    }

    hd += __shfl_xor(hd, 16);
    hd += __shfl_xor(hd, 32);
    if (lane < 16)
        out[blk*16 + s] = 1.f / (1.f + __expf(-(hd + bo[0])));
}

extern "C" void kernel_launch(void* const* d_in, const int* in_sizes, int n_in,
                              void* d_out, int out_size, void* d_ws, size_t ws_size,
                              hipStream_t stream) {
    const float* mod_fea = (const float*)d_in[0];
    const float* W1 = (const float*)d_in[1];
    const float* b1 = (const float*)d_in[2];
    const float* W2 = (const float*)d_in[3];
    const float* b2 = (const float*)d_in[4];
    const float* W3 = (const float*)d_in[5];
    const float* b3 = (const float*)d_in[6];
    const float* We = (const float*)d_in[7];
    const float* be = (const float*)d_in[8];
    const float* Wd1 = (const float*)d_in[9];
    const float* bd1 = (const float*)d_in[10];
    const float* Wd2 = (const float*)d_in[11];
    const float* bd2 = (const float*)d_in[12];
    const float* Wq = (const float*)d_in[13];
    const float* Wk = (const float*)d_in[14];
    const float* Wv = (const float*)d_in[15];
    const float* Wo = (const float*)d_in[16];
    const float* bo = (const float*)d_in[17];
    float* ws  = (float*)d_ws;
    float* out = (float*)d_out;

    hipLaunchKernelGGL(table_kernel, dim3(45), dim3(256), 0, stream,
                       We, be, Wq, Wk, Wv, Wd1, bd1, Wo, Wd2, W1, W2, W3, ws);
    hipLaunchKernelGGL(autoint_kernel, dim3(BATCH/16), dim3(64), 0, stream,
                       mod_fea, b1, b2, b3, bd2, Wo, bo, ws, out);
}

// Round 10
// 30.084 us; speedup vs baseline: 3.4225x; 1.1086x over previous
//
#include <hip/hip_runtime.h>
#include <math.h>

#define BATCH 16384

// ---- ws float offsets ----
#define RT    0        // [192][20] {TQ4,BQ4,We4,be4,Wo4}  (TQ/BQ pre-scaled 0.5)
#define A0T   3840     // [32]
#define CD1   3872     // [32]
#define SBKV  3904     // [16]  0-7 SK const, 8-15 SV const
#define WD2T  3920     // [16][32]
#define FB    4432     // fragment files: 99 frags x 64 lanes x 4 dwords (bf16-packed)
// frag ids: W1F: m*8+kt*4+ot (0..47) | W2F: 48+m*4+kt*2+ot (48..71) | W3F: 72+m (72..77)
//           AGF: 78+kt*2+ot (78..89) | ADF: 90+kt*2+ot (90..95)    | ASF: 96+kt (96..98)

typedef __attribute__((ext_vector_type(8))) short short8;
typedef __attribute__((ext_vector_type(4))) float f32x4;

union FRAG { int4 i; short8 s; };

__device__ __forceinline__ unsigned pkbf(float a, float b) {
    unsigned ua = __float_as_uint(a); ua += 0x7FFFu + ((ua >> 16) & 1u);
    unsigned ub = __float_as_uint(b); ub += 0x7FFFu + ((ub >> 16) & 1u);
    return (ua >> 16) | (ub & 0xFFFF0000u);
}

#define MFMA(A, B, C) __builtin_amdgcn_mfma_f32_16x16x32_bf16((A), (B), (C), 0, 0, 0)

// ---------------- table kernel (unchanged from R9) ----------------
__global__ __launch_bounds__(256) void table_kernel(
    const float* __restrict__ We, const float* __restrict__ be,
    const float* __restrict__ Wq, const float* __restrict__ Wk,
    const float* __restrict__ Wv, const float* __restrict__ Wd1,
    const float* __restrict__ bd1, const float* __restrict__ Wo,
    const float* __restrict__ Wd2,
    const float* __restrict__ W1, const float* __restrict__ W2,
    const float* __restrict__ W3,
    float* __restrict__ ws)
{
    int t = blockIdx.x * 256 + threadIdx.x;
    if (t < 3840) {                              // ROWTAB
        int r = t / 20, c = t % 20;
        int h = r / 96, q = r % 96;
        float v;
        if (c < 4) {
            float a = 0.f;
            #pragma unroll
            for (int i = 0; i < 8; ++i) a += We[q*8+i] * Wq[i*8 + h*4 + c];
            v = 0.5f * a;
        } else if (c < 8) {
            float a = 0.f;
            #pragma unroll
            for (int i = 0; i < 8; ++i) a += be[q*8+i] * Wq[i*8 + h*4 + (c-4)];
            v = 0.5f * a;
        } else if (c < 12) {
            v = We[q*8 + h*4 + (c-8)];
        } else if (c < 16) {
            v = be[q*8 + h*4 + (c-12)];
        } else {
            v = Wo[16 + q*8 + h*4 + (c-16)];
        }
        ws[RT + t] = v;
    } else if (t < 4096) {                       // A0T: 32 g x 8 chunks
        int l = t - 3840, g = l >> 3, c = l & 7;
        int h = g >> 4, d = (g >> 2) & 3, e = g & 3;
        float acc = 0.f;
        for (int tok = c*12; tok < c*12 + 12; ++tok) {
            float bk = 0.f, bv = 0.f;
            #pragma unroll
            for (int j = 0; j < 8; ++j) {
                float b = be[tok*8+j];
                bk += b * Wk[j*8 + h*4 + d];
                bv += b * Wv[j*8 + h*4 + e];
            }
            acc += bk * bv;
        }
        acc += __shfl_xor(acc,1); acc += __shfl_xor(acc,2); acc += __shfl_xor(acc,4);
        if (c == 0) ws[A0T + g] = acc;
    } else if (t < 4352) {                       // CD1: 32 g x 8 chunks
        int l = t - 4096, g = l >> 3, c = l & 7;
        float acc = 0.f;
        for (int i = c*96; i < c*96 + 96; ++i) acc += be[i] * Wd1[i*32 + g];
        acc += __shfl_xor(acc,1); acc += __shfl_xor(acc,2); acc += __shfl_xor(acc,4);
        if (c == 0) ws[CD1 + g] = acc + bd1[g];
    } else if (t < 4608) {                       // SBKV: 16 x 16 chunks
        int l = t - 4352, idx = l >> 4, c = l & 15;
        int isV = idx >> 3, d = idx & 7;
        const float* W = isV ? Wv : Wk;
        float acc = 0.f;
        for (int i = c*48; i < c*48 + 48; ++i) acc += be[i] * W[(i & 7)*8 + d];
        acc += __shfl_xor(acc,1); acc += __shfl_xor(acc,2);
        acc += __shfl_xor(acc,4); acc += __shfl_xor(acc,8);
        if (c == 0) ws[SBKV + idx] = acc;
    } else if (t < 5120) {                       // WD2T [16][32]
        int l = t - 4608, o = l >> 5, k = l & 31;
        ws[WD2T + l] = Wd2[k*16 + o];
    } else if (t < 11456) {                      // fragment files
        int l = t - 5120, fi = l >> 6, lane = l & 63;
        int g = lane >> 4, c = lane & 15;
        float v[8];
        if (fi < 48) {                           // W1F
            int m = fi >> 3, kt = (fi >> 2) & 1, ot = fi & 3;
            #pragma unroll
            for (int j = 0; j < 8; ++j) {
                int k = kt*32 + g*8 + j;
                v[j] = (k < 40) ? W1[(m*40 + k)*64 + ot*16 + c] : 0.f;
            }
        } else if (fi < 72) {                    // W2F
            int x = fi - 48, m = x >> 2, kt = (x >> 1) & 1, ot = x & 1;
            #pragma unroll
            for (int j = 0; j < 8; ++j) {
                int k = kt*32 + g*8 + j;
                v[j] = W2[(m*64 + k)*32 + ot*16 + c];
            }
        } else if (fi < 78) {                    // W3F
            int m = fi - 72;
            #pragma unroll
            for (int j = 0; j < 8; ++j)
                v[j] = W3[(m*32 + g*8 + j)*16 + c];
        } else if (fi < 90) {                    // AGF
            int x = fi - 78, kt = x >> 1, ot = x & 1, row = ot*16 + c;
            int hh = row >> 4, d = (row >> 2) & 3, e = row & 3;
            #pragma unroll
            for (int j = 0; j < 8; ++j) {
                int k = kt*32 + g*8 + j;
                int tok = (k < 96) ? k : (k - 96);
                float tk = 0.f, bk = 0.f, tv = 0.f, bv = 0.f;
                #pragma unroll
                for (int j8 = 0; j8 < 8; ++j8) {
                    float we = We[tok*8+j8], b = be[tok*8+j8];
                    tk += we * Wk[j8*8 + hh*4 + d]; bk += b * Wk[j8*8 + hh*4 + d];
                    tv += we * Wv[j8*8 + hh*4 + e]; bv += b * Wv[j8*8 + hh*4 + e];
                }
                v[j] = (k < 96) ? (tk*bv + bk*tv) : (tk*tv);
            }
        } else if (fi < 96) {                    // ADF
            int x = fi - 90, kt = x >> 1, ot = x & 1, row = ot*16 + c;
            #pragma unroll
            for (int j = 0; j < 8; ++j) {
                int tok = kt*32 + g*8 + j;
                float a = 0.f;
                #pragma unroll
                for (int j8 = 0; j8 < 8; ++j8)
                    a += We[tok*8+j8] * Wd1[(tok*8+j8)*32 + row];
                v[j] = a;
            }
        } else {                                 // ASF
            int kt = fi - 96, row = c, d = row & 7;
            const float* W = (row < 8) ? Wk : Wv;
            #pragma unroll
            for (int j = 0; j < 8; ++j) {
                int tok = kt*32 + g*8 + j;
                float a = 0.f;
                #pragma unroll
                for (int j8 = 0; j8 < 8; ++j8)
                    a += We[tok*8+j8] * W[j8*8 + d];
                v[j] = a;
            }
        }
        float* dst = ws + FB + (fi*64 + lane)*4;
        dst[0] = __uint_as_float(pkbf(v[0], v[1]));
        dst[1] = __uint_as_float(pkbf(v[2], v[3]));
        dst[2] = __uint_as_float(pkbf(v[4], v[5]));
        dst[3] = __uint_as_float(pkbf(v[6], v[7]));
    }
}

// ---------------- main kernel: 2 waves / 16 samples per block ----------------
__global__ __launch_bounds__(128) void autoint_kernel(
    const float* __restrict__ mod_fea,
    const float* __restrict__ b1, const float* __restrict__ b2,
    const float* __restrict__ b3, const float* __restrict__ bd2,
    const float* __restrict__ Wo, const float* __restrict__ bo,
    const float* __restrict__ ws,
    float* __restrict__ out)
{
    const int tid  = threadIdx.x;
    const int lane = tid & 63;
    const int wv   = tid >> 6;           // 0,1
    const int g = lane >> 4, c = lane & 15;
    const int blk = blockIdx.x;

    __shared__ unsigned int   xbuf[16*124];     // bf16-packed x rows [s][120 pairs + pad]
    __shared__ unsigned short h1buf[2][16*72];  // per-wave
    __shared__ unsigned short h2buf[2][16*40];
    __shared__ unsigned short fbuf [16*200];    // [s][flat 96 | flat2 96 | pad]
    __shared__ float s_stat[80*17];
    __shared__ float s_part[32];

    // ---- stage input: coalesced float4 -> bf16 LDS ----
    {
        const float* xin = mod_fea + (size_t)blk * 3840;
        #pragma unroll
        for (int i = 0; i < 8; ++i) {
            int idx = tid + i*128;
            if (idx < 960) {
                float4 v = *(const float4*)(xin + idx*4);
                int s = idx / 60, fq = idx - s*60;
                xbuf[s*124 + fq*2]     = pkbf(v.x, v.y);
                xbuf[s*124 + fq*2 + 1] = pkbf(v.z, v.w);
            }
        }
    }
    __syncthreads();

    const int4* fragp = (const int4*)(ws + FB);

    // ---- stage A: wave w runs modules 3w..3w+2 ----
    #pragma unroll
    for (int mm = 0; mm < 3; ++mm) {
        const int m = wv*3 + mm;
        FRAG bx0, bx1;
        bx0.i = *(const int4*)(&xbuf[c*124 + (m*40 + g*8)/2]);
        if (g == 0) bx1.i = *(const int4*)(&xbuf[c*124 + (m*40 + 32)/2]);
        else        bx1.i = make_int4(0,0,0,0);

        // M1: h1[64][16]
        #pragma unroll
        for (int ot = 0; ot < 4; ++ot) {
            FRAG a0, a1;
            a0.i = fragp[(m*8 + 0*4 + ot)*64 + lane];
            a1.i = fragp[(m*8 + 1*4 + ot)*64 + lane];
            f32x4 acc = {0.f, 0.f, 0.f, 0.f};
            acc = MFMA(a0.s, bx0.s, acc);
            acc = MFMA(a1.s, bx1.s, acc);
            float4 bb = *(const float4*)(b1 + m*64 + ot*16 + g*4);
            float r0 = fmaxf(acc[0] + bb.x, 0.f);
            float r1 = fmaxf(acc[1] + bb.y, 0.f);
            float r2 = fmaxf(acc[2] + bb.z, 0.f);
            float r3 = fmaxf(acc[3] + bb.w, 0.f);
            *(uint2*)(&h1buf[wv][c*72 + ot*16 + g*4]) = make_uint2(pkbf(r0,r1), pkbf(r2,r3));
        }

        // M2: h2[32][16]
        FRAG bh0, bh1;
        bh0.i = *(const int4*)(&h1buf[wv][c*72 + 0*32 + g*8]);
        bh1.i = *(const int4*)(&h1buf[wv][c*72 + 1*32 + g*8]);
        #pragma unroll
        for (int ot = 0; ot < 2; ++ot) {
            FRAG a0, a1;
            a0.i = fragp[(48 + m*4 + 0*2 + ot)*64 + lane];
            a1.i = fragp[(48 + m*4 + 1*2 + ot)*64 + lane];
            f32x4 acc = {0.f, 0.f, 0.f, 0.f};
            acc = MFMA(a0.s, bh0.s, acc);
            acc = MFMA(a1.s, bh1.s, acc);
            float4 bb = *(const float4*)(b2 + m*32 + ot*16 + g*4);
            float r0 = fmaxf(acc[0] + bb.x, 0.f);
            float r1 = fmaxf(acc[1] + bb.y, 0.f);
            float r2 = fmaxf(acc[2] + bb.z, 0.f);
            float r3 = fmaxf(acc[3] + bb.w, 0.f);
            *(uint2*)(&h2buf[wv][c*40 + ot*16 + g*4]) = make_uint2(pkbf(r0,r1), pkbf(r2,r3));
        }

        // M3: flat[16][16]
        {
            FRAG bh2, a;
            bh2.i = *(const int4*)(&h2buf[wv][c*40 + g*8]);
            a.i   = fragp[(72 + m)*64 + lane];
            f32x4 acc = {0.f, 0.f, 0.f, 0.f};
            acc = MFMA(a.s, bh2.s, acc);
            float4 bb = *(const float4*)(b3 + m*16 + g*4);
            float r0 = fmaxf(acc[0] + bb.x, 0.f);
            float r1 = fmaxf(acc[1] + bb.y, 0.f);
            float r2 = fmaxf(acc[2] + bb.z, 0.f);
            float r3 = fmaxf(acc[3] + bb.w, 0.f);
            *(uint2*)(&fbuf[c*200 + m*16 + g*4]) =
                make_uint2(pkbf(r0,r1), pkbf(r2,r3));
            *(uint2*)(&fbuf[c*200 + 96 + m*16 + g*4]) =
                make_uint2(pkbf(r0*r0, r1*r1), pkbf(r2*r2, r3*r3));
        }
    }
    __syncthreads();

    // ---- P4: stats via MFMA, split across waves ----
    {
        FRAG bf0, bf1, bf2, bf3, bf4, bf5;
        bf0.i = *(const int4*)(&fbuf[c*200 + 0*32 + g*8]);
        bf1.i = *(const int4*)(&fbuf[c*200 + 1*32 + g*8]);
        bf2.i = *(const int4*)(&fbuf[c*200 + 2*32 + g*8]);
        bf3.i = *(const int4*)(&fbuf[c*200 + 3*32 + g*8]);
        bf4.i = *(const int4*)(&fbuf[c*200 + 4*32 + g*8]);
        bf5.i = *(const int4*)(&fbuf[c*200 + 5*32 + g*8]);

        if (wv == 0) {
            // G (rows 0..31)
            #pragma unroll
            for (int ot = 0; ot < 2; ++ot) {
                f32x4 acc = {0.f, 0.f, 0.f, 0.f};
                FRAG a;
                a.i = fragp[(78 + 0*2 + ot)*64 + lane]; acc = MFMA(a.s, bf0.s, acc);
                a.i = fragp[(78 + 1*2 + ot)*64 + lane]; acc = MFMA(a.s, bf1.s, acc);
                a.i = fragp[(78 + 2*2 + ot)*64 + lane]; acc = MFMA(a.s, bf2.s, acc);
                a.i = fragp[(78 + 3*2 + ot)*64 + lane]; acc = MFMA(a.s, bf3.s, acc);
                a.i = fragp[(78 + 4*2 + ot)*64 + lane]; acc = MFMA(a.s, bf4.s, acc);
                a.i = fragp[(78 + 5*2 + ot)*64 + lane]; acc = MFMA(a.s, bf5.s, acc);
                float4 a0 = *(const float4*)(ws + A0T + ot*16 + g*4);
                int row = ot*16 + g*4;
                s_stat[(row+0)*17 + c] = acc[0] + a0.x;
                s_stat[(row+1)*17 + c] = acc[1] + a0.y;
                s_stat[(row+2)*17 + c] = acc[2] + a0.z;
                s_stat[(row+3)*17 + c] = acc[3] + a0.w;
            }
        } else {
            // SK/SV (rows 32..47)
            {
                f32x4 acc = {0.f, 0.f, 0.f, 0.f};
                FRAG a;
                a.i = fragp[(96 + 0)*64 + lane]; acc = MFMA(a.s, bf0.s, acc);
                a.i = fragp[(96 + 1)*64 + lane]; acc = MFMA(a.s, bf1.s, acc);
                a.i = fragp[(96 + 2)*64 + lane]; acc = MFMA(a.s, bf2.s, acc);
                float4 sb = *(const float4*)(ws + SBKV + g*4);
                int row = 32 + g*4;
                s_stat[(row+0)*17 + c] = acc[0] + sb.x;
                s_stat[(row+1)*17 + c] = acc[1] + sb.y;
                s_stat[(row+2)*17 + c] = acc[2] + sb.z;
                s_stat[(row+3)*17 + c] = acc[3] + sb.w;
            }
            // d1 (rows 48..79)
            #pragma unroll
            for (int ot = 0; ot < 2; ++ot) {
                f32x4 acc = {0.f, 0.f, 0.f, 0.f};
                FRAG a;
                a.i = fragp[(90 + 0*2 + ot)*64 + lane]; acc = MFMA(a.s, bf0.s, acc);
                a.i = fragp[(90 + 1*2 + ot)*64 + lane]; acc = MFMA(a.s, bf1.s, acc);
                a.i = fragp[(90 + 2*2 + ot)*64 + lane]; acc = MFMA(a.s, bf2.s, acc);
                float4 cd = *(const float4*)(ws + CD1 + ot*16 + g*4);
                int row = 48 + ot*16 + g*4;
                s_stat[(row+0)*17 + c] = fmaxf(acc[0] + cd.x, 0.f);
                s_stat[(row+1)*17 + c] = fmaxf(acc[1] + cd.y, 0.f);
                s_stat[(row+2)*17 + c] = fmaxf(acc[2] + cd.z, 0.f);
                s_stat[(row+3)*17 + c] = fmaxf(acc[3] + cd.w, 0.f);
            }
        }
    }
    __syncthreads();

    // ---- P5: attention rows (24/thread) + dnn2 + head ----
    const int s  = tid & 15;
    const int rg = tid >> 4;         // 0..7
    const int h  = rg >> 2;
    const int q0 = (rg & 3) * 24;

    float Gr[16], SKr[4], SVr[4];
    #pragma unroll
    for (int i = 0; i < 16; ++i) Gr[i] = s_stat[(h*16 + i)*17 + s];
    #pragma unroll
    for (int d = 0; d < 4; ++d) {
        SKr[d] = s_stat[(32 + h*4 + d)*17 + s];
        SVr[d] = s_stat[(40 + h*4 + d)*17 + s];
    }

    float hd = 0.f;
    const float* rtb = ws + RT + h*1920;

    #pragma unroll 4
    for (int q = q0; q < q0 + 24; ++q) {
        const float* rt = rtb + q*20;
        float4 rt0 = *(const float4*)(rt);
        float4 rt1 = *(const float4*)(rt+4);
        float4 rt2 = *(const float4*)(rt+8);
        float4 rt3 = *(const float4*)(rt+12);
        float4 rt4 = *(const float4*)(rt+16);
        float fq = __uint_as_float(((unsigned)fbuf[s*200 + q]) << 16);
        float qq0 = fmaf(fq, rt0.x, rt1.x), qq1 = fmaf(fq, rt0.y, rt1.y);
        float qq2 = fmaf(fq, rt0.z, rt1.z), qq3 = fmaf(fq, rt0.w, rt1.w);
        float den = 96.f;
        den = fmaf(qq0, SKr[0], den); den = fmaf(qq1, SKr[1], den);
        den = fmaf(qq2, SKr[2], den); den = fmaf(qq3, SKr[3], den);
        float n0 = SVr[0], n1 = SVr[1], n2 = SVr[2], n3 = SVr[3];
        n0 = fmaf(qq0, Gr[ 0], n0); n1 = fmaf(qq0, Gr[ 1], n1);
        n2 = fmaf(qq0, Gr[ 2], n2); n3 = fmaf(qq0, Gr[ 3], n3);
        n0 = fmaf(qq1, Gr[ 4], n0); n1 = fmaf(qq1, Gr[ 5], n1);
        n2 = fmaf(qq1, Gr[ 6], n2); n3 = fmaf(qq1, Gr[ 7], n3);
        n0 = fmaf(qq2, Gr[ 8], n0); n1 = fmaf(qq2, Gr[ 9], n1);
        n2 = fmaf(qq2, Gr[10], n2); n3 = fmaf(qq2, Gr[11], n3);
        n0 = fmaf(qq3, Gr[12], n0); n1 = fmaf(qq3, Gr[13], n1);
        n2 = fmaf(qq3, Gr[14], n2); n3 = fmaf(qq3, Gr[15], n3);
        float rc = __builtin_amdgcn_rcpf(den);
        float a0 = fmaxf(fmaf(n0, rc, fmaf(fq, rt2.x, rt3.x)), 0.f);
        float a1 = fmaxf(fmaf(n1, rc, fmaf(fq, rt2.y, rt3.y)), 0.f);
        float a2 = fmaxf(fmaf(n2, rc, fmaf(fq, rt2.z, rt3.z)), 0.f);
        float a3 = fmaxf(fmaf(n3, rc, fmaf(fq, rt2.w, rt3.w)), 0.f);
        hd = fmaf(a0, rt4.x, hd); hd = fmaf(a1, rt4.y, hd);
        hd = fmaf(a2, rt4.z, hd); hd = fmaf(a3, rt4.w, hd);
    }

    // dnn2: 2 outputs per thread (o = rg*2 + jj)
    {
        float d1r[32];
        #pragma unroll
        for (int k = 0; k < 32; ++k) d1r[k] = s_stat[(48 + k)*17 + s];
        #pragma unroll
        for (int jj = 0; jj < 2; ++jj) {
            int o = rg*2 + jj;
            float acc = bd2[o];
            const float* wp = ws + WD2T + o*32;
            #pragma unroll
            for (int k = 0; k < 32; ++k) acc = fmaf(d1r[k], wp[k], acc);
            hd = fmaf(fmaxf(acc, 0.f), Wo[o], hd);
        }
    }

    // reduce across row-groups: within wave (lanes s, s+16, s+32, s+48), then cross-wave
    hd += __shfl_xor(hd, 16);
    hd += __shfl_xor(hd, 32);
    if (lane < 16) s_part[wv*16 + lane] = hd;
    __syncthreads();
    if (tid < 16)
        out[blk*16 + tid] = 1.f / (1.f + __expf(-(s_part[tid] + s_part[16+tid] + bo[0])));
}

extern "C" void kernel_launch(void* const* d_in, const int* in_sizes, int n_in,
                              void* d_out, int out_size, void* d_ws, size_t ws_size,
                              hipStream_t stream) {
    const float* mod_fea = (const float*)d_in[0];
    const float* W1 = (const float*)d_in[1];
    const float* b1 = (const float*)d_in[2];
    const float* W2 = (const float*)d_in[3];
    const float* b2 = (const float*)d_in[4];
    const float* W3 = (const float*)d_in[5];
    const float* b3 = (const float*)d_in[6];
    const float* We = (const float*)d_in[7];
    const float* be = (const float*)d_in[8];
    const float* Wd1 = (const float*)d_in[9];
    const float* bd1 = (const float*)d_in[10];
    const float* Wd2 = (const float*)d_in[11];
    const float* bd2 = (const float*)d_in[12];
    const float* Wq = (const float*)d_in[13];
    const float* Wk = (const float*)d_in[14];
    const float* Wv = (const float*)d_in[15];
    const float* Wo = (const float*)d_in[16];
    const float* bo = (const float*)d_in[17];
    float* ws  = (float*)d_ws;
    float* out = (float*)d_out;

    hipLaunchKernelGGL(table_kernel, dim3(45), dim3(256), 0, stream,
                       We, be, Wq, Wk, Wv, Wd1, bd1, Wo, Wd2, W1, W2, W3, ws);
    hipLaunchKernelGGL(autoint_kernel, dim3(BATCH/16), dim3(128), 0, stream,
                       mod_fea, b1, b2, b3, bd2, Wo, bo, ws, out);
}